// Round 1
// baseline (107.170 us; speedup 1.0000x reference)
//
#include <hip/hip_runtime.h>
#include <math.h>

// Problem constants (fixed by setup_inputs)
#define B_  16
#define C_  512
#define CR_ 128
#define N_  4096
#define CSPLIT 4

static constexpr float BN_EPS_F = 1e-5f;

// ---------------------------------------------------------------------------
// K1: partial channel colsum.  s_part[cs][b][n] = sum_{c in chunk cs} x[b,c,n]
// grid = (N/256, B, CSPLIT), block = 256.  Coalesced: lane i reads n0+i.
// ---------------------------------------------------------------------------
__global__ void k1_colsum_part(const float* __restrict__ x,
                               float* __restrict__ s_part) {
    const int n  = blockIdx.x * 256 + threadIdx.x;
    const int b  = blockIdx.y;
    const int cs = blockIdx.z;
    const float* xp = x + ((size_t)b * C_ + (size_t)cs * (C_ / CSPLIT)) * N_ + n;
    float acc = 0.f;
#pragma unroll 8
    for (int c = 0; c < C_ / CSPLIT; ++c)
        acc += xp[(size_t)c * N_];
    s_part[((size_t)cs * B_ + b) * N_ + n] = acc;
}

// ---------------------------------------------------------------------------
// K1b: s[b,n] = sum_cs s_part[cs][b][n]   (B*N = 65536 elements)
// ---------------------------------------------------------------------------
__global__ void k1b_reduce(const float* __restrict__ s_part,
                           float* __restrict__ s) {
    const int i = blockIdx.x * 256 + threadIdx.x;   // [0, B_*N_)
    float acc = 0.f;
#pragma unroll
    for (int cs = 0; cs < CSPLIT; ++cs)
        acc += s_part[(size_t)cs * B_ * N_ + i];
    s[i] = acc;
}

// ---------------------------------------------------------------------------
// K2: att[b,c] = sum_n x[b,c,n] * s[b,n].  One wave (64 lanes) per row.
// block = 256 (4 waves), grid = B*C/4 = 2048.  float4 loads, 1 KiB/wave-instr.
// ---------------------------------------------------------------------------
__global__ void k2_att(const float* __restrict__ x,
                       const float* __restrict__ s,
                       float* __restrict__ att) {
    const int wave = threadIdx.x >> 6;
    const int lane = threadIdx.x & 63;
    const int row  = blockIdx.x * 4 + wave;   // [0, B_*C_)
    const int b    = row >> 9;                // row / C_
    const float4* xp = (const float4*)(x + (size_t)row * N_);
    const float4* sp = (const float4*)(s + (size_t)b * N_);
    float acc = 0.f;
#pragma unroll
    for (int k = 0; k < N_ / 4 / 64; ++k) {   // 16 iters
        float4 xv = xp[k * 64 + lane];
        float4 sv = sp[k * 64 + lane];
        acc += xv.x * sv.x + xv.y * sv.y + xv.z * sv.z + xv.w * sv.w;
    }
#pragma unroll
    for (int off = 32; off >= 1; off >>= 1)
        acc += __shfl_down(acc, off, 64);
    if (lane == 0) att[row] = acc;
}

// ---------------------------------------------------------------------------
// K3a: h[b,o] = relu(BN(sum_c W1[o,c] * att[b,c]))  — wave per output.
// B*CR = 2048 outputs; block 256 (4 waves), grid 512.
// ---------------------------------------------------------------------------
__global__ void k3a_h(const float* __restrict__ W1,
                      const float* __restrict__ att,
                      const float* __restrict__ gamma,
                      const float* __restrict__ beta,
                      const float* __restrict__ rmean,
                      const float* __restrict__ rvar,
                      float* __restrict__ h) {
    const int wave = threadIdx.x >> 6;
    const int lane = threadIdx.x & 63;
    const int idx  = blockIdx.x * 4 + wave;   // [0, B_*CR_)
    const int b = idx >> 7;                   // / CR_
    const int o = idx & (CR_ - 1);
    const float* w  = W1  + (size_t)o * C_;
    const float* at = att + (size_t)b * C_;
    float acc = 0.f;
#pragma unroll
    for (int k = 0; k < C_ / 64; ++k)         // 8 iters
        acc += w[k * 64 + lane] * at[k * 64 + lane];
#pragma unroll
    for (int off = 32; off >= 1; off >>= 1)
        acc += __shfl_down(acc, off, 64);
    if (lane == 0) {
        float v = gamma[o] * (acc - rmean[o]) * rsqrtf(rvar[o] + BN_EPS_F) + beta[o];
        h[idx] = fmaxf(v, 0.f);
    }
}

// ---------------------------------------------------------------------------
// K3b: a[b,j] = sigmoid(sum_k W2[j,k] * h[b,k])  — wave per output.
// B*C = 8192 outputs; block 256 (4 waves), grid 2048.
// ---------------------------------------------------------------------------
__global__ void k3b_a(const float* __restrict__ W2,
                      const float* __restrict__ h,
                      float* __restrict__ a) {
    const int wave = threadIdx.x >> 6;
    const int lane = threadIdx.x & 63;
    const int idx  = blockIdx.x * 4 + wave;   // [0, B_*C_)
    const int b = idx >> 9;                   // / C_
    const int j = idx & (C_ - 1);
    const float* w  = W2 + (size_t)j * CR_;
    const float* hp = h  + (size_t)b * CR_;
    float acc = w[lane] * hp[lane] + w[64 + lane] * hp[64 + lane];
#pragma unroll
    for (int off = 32; off >= 1; off >>= 1)
        acc += __shfl_down(acc, off, 64);
    if (lane == 0) a[idx] = 1.f / (1.f + expf(-acc));
}

// ---------------------------------------------------------------------------
// K4: out[b,c,n] = x[b,c,n] * a[b,c].  float4 grid-stride.
// ---------------------------------------------------------------------------
__global__ void k4_scale(const float* __restrict__ x,
                         const float* __restrict__ a,
                         float* __restrict__ out) {
    const size_t total4 = (size_t)B_ * C_ * N_ / 4;
    const size_t stride = (size_t)gridDim.x * blockDim.x;
    for (size_t i = (size_t)blockIdx.x * blockDim.x + threadIdx.x;
         i < total4; i += stride) {
        const size_t row = i >> 10;           // / (N_/4)
        const float av = a[row];
        float4 xv = ((const float4*)x)[i];
        float4 ov;
        ov.x = xv.x * av; ov.y = xv.y * av;
        ov.z = xv.z * av; ov.w = xv.w * av;
        ((float4*)out)[i] = ov;
    }
}

// ---------------------------------------------------------------------------
extern "C" void kernel_launch(void* const* d_in, const int* in_sizes, int n_in,
                              void* d_out, int out_size, void* d_ws, size_t ws_size,
                              hipStream_t stream) {
    const float* x     = (const float*)d_in[0];
    const float* W1    = (const float*)d_in[1];
    const float* gamma = (const float*)d_in[2];
    const float* beta  = (const float*)d_in[3];
    const float* rmean = (const float*)d_in[4];
    const float* rvar  = (const float*)d_in[5];
    const float* W2    = (const float*)d_in[6];
    float* out = (float*)d_out;

    // Workspace layout (floats)
    float* ws     = (float*)d_ws;
    float* s_part = ws;                                  // CSPLIT*B*N = 262144
    float* s      = s_part + (size_t)CSPLIT * B_ * N_;   // B*N = 65536
    float* att    = s + (size_t)B_ * N_;                 // B*C = 8192
    float* h      = att + (size_t)B_ * C_;               // B*CR = 2048
    float* a      = h + (size_t)B_ * CR_;                // B*C = 8192

    k1_colsum_part<<<dim3(N_ / 256, B_, CSPLIT), 256, 0, stream>>>(x, s_part);
    k1b_reduce<<<dim3(B_ * N_ / 256), 256, 0, stream>>>(s_part, s);
    k2_att<<<dim3(B_ * C_ / 4), 256, 0, stream>>>(x, s, att);
    k3a_h<<<dim3(B_ * CR_ / 4), 256, 0, stream>>>(W1, att, gamma, beta, rmean, rvar, h);
    k3b_a<<<dim3(B_ * C_ / 4), 256, 0, stream>>>(W2, h, a);
    k4_scale<<<dim3(2048), 256, 0, stream>>>(x, a, out);
}